// Round 9
// baseline (229.131 us; speedup 1.0000x reference)
//
#include <hip/hip_runtime.h>
#include <math.h>

#define H_IMG 64
#define W_IMG 64
#define PIX   (H_IMG * W_IMG)   // 4096
#define NB    4
#define NHEADS 8
#define HD    32
#define CDIM  256
#define QKV_C 768
#define ATT_SCALE 0.17677669529663687f  // 32^-0.5

typedef _Float16 half8_t __attribute__((ext_vector_type(8)));
typedef _Float16 half2_t __attribute__((ext_vector_type(2)));
typedef float f32x4 __attribute__((ext_vector_type(4)));

// ----------------------------------------------------------------------------
// Transpose+convert x [b][C][PIX] f32 -> [b][PIX][C] f16, AND (z==NB slice)
// convert both weight matrices to fp16. One dispatch instead of two.
// ----------------------------------------------------------------------------
__launch_bounds__(256)
__global__ void transpose_cvt(const float* __restrict__ src, _Float16* __restrict__ dst,
                              const float* __restrict__ w1, int n1,
                              const float* __restrict__ w2, int n2,
                              _Float16* __restrict__ d1, _Float16* __restrict__ d2) {
    const int tx = threadIdx.x;
    const int ty = threadIdx.y;
    if (blockIdx.z == NB) {
        // weight conversion: 256 blocks x 256 threads, grid-stride
        const int bid = blockIdx.y * 64 + blockIdx.x;          // 0..255
        int tid = bid * 256 + ty * 64 + tx;                    // 0..65535
        const int total = n1 + n2;
        for (int i = tid; i < total; i += 65536) {
            if (i < n1) d1[i] = (_Float16)w1[i];
            else        d2[i - n1] = (_Float16)w2[i - n1];
        }
        return;
    }
    __shared__ _Float16 tl[64][66];
    const int b  = blockIdx.z;
    const int p0 = blockIdx.x * 64;
    const int c0 = blockIdx.y * 64;
    const float* s = src + (size_t)b * CDIM * PIX;
    _Float16* d = dst + (size_t)b * PIX * CDIM;
#pragma unroll
    for (int cc = ty; cc < 64; cc += 4)
        tl[cc][tx] = (_Float16)s[(size_t)(c0 + cc) * PIX + p0 + tx];
    __syncthreads();
#pragma unroll
    for (int pp = ty; pp < 64; pp += 4)
        d[(size_t)(p0 + pp) * CDIM + c0 + tx] = tl[tx][pp];
}

// ----------------------------------------------------------------------------
// fp16 MFMA GEMM: Y[b][m][n] = sum_k A[m][k] * BT[b][n][k] + bias[m]
// PAIR=true: output pair-interleaved [m/2][n][2] for packed-fp16 attention.
// ----------------------------------------------------------------------------
template <typename OutT, bool PAIR>
__launch_bounds__(256)
__global__ void gemm16(const _Float16* __restrict__ A,
                       const _Float16* __restrict__ BT,
                       const float* __restrict__ bias,
                       OutT* __restrict__ Y,
                       int M, int K, int N) {
    __shared__ _Float16 Asl[128][40];
    __shared__ _Float16 Bsl[128][40];
    const int b = blockIdx.z;
    const _Float16* Bb = BT + (size_t)b * N * K;
    OutT* Yb = Y + (size_t)b * M * N;
    const int m0 = blockIdx.y * 128;
    const int n0 = blockIdx.x * 128;
    const int t    = threadIdx.x;
    const int lane = t & 63;
    const int w    = t >> 6;
    const int wm = w >> 1, wn = w & 1;
    const int l15 = lane & 15;
    const int kq  = (lane >> 4) * 8;

    f32x4 acc[4][4];
#pragma unroll
    for (int mt = 0; mt < 4; mt++)
#pragma unroll
        for (int nt = 0; nt < 4; nt++)
            acc[mt][nt] = (f32x4){0.f, 0.f, 0.f, 0.f};

    for (int k0 = 0; k0 < K; k0 += 32) {
        __syncthreads();
#pragma unroll
        for (int i = 0; i < 2; i++) {
            int idx = t + i * 256;
            int row = idx >> 2;
            int seg = (idx & 3) * 8;
            *(half8_t*)&Asl[row][seg] = *(const half8_t*)(A  + (size_t)(m0 + row) * K + k0 + seg);
            *(half8_t*)&Bsl[row][seg] = *(const half8_t*)(Bb + (size_t)(n0 + row) * K + k0 + seg);
        }
        __syncthreads();
        half8_t af[4], bf[4];
#pragma unroll
        for (int mt = 0; mt < 4; mt++)
            af[mt] = *(const half8_t*)&Asl[wm * 64 + mt * 16 + l15][kq];
#pragma unroll
        for (int nt = 0; nt < 4; nt++)
            bf[nt] = *(const half8_t*)&Bsl[wn * 64 + nt * 16 + l15][kq];
#pragma unroll
        for (int mt = 0; mt < 4; mt++)
#pragma unroll
            for (int nt = 0; nt < 4; nt++)
                acc[mt][nt] = __builtin_amdgcn_mfma_f32_16x16x32_f16(
                    af[mt], bf[nt], acc[mt][nt], 0, 0, 0);
    }

    const int rq = lane >> 4;
    if constexpr (PAIR) {
        unsigned* Yp = (unsigned*)Yb;   // (M/2) x N dwords
#pragma unroll
        for (int mt = 0; mt < 4; mt++) {
#pragma unroll
            for (int s = 0; s < 2; s++) {
                int mp = m0 + wm * 64 + mt * 16 + rq * 4 + 2 * s;
                float b0 = bias[mp], b1 = bias[mp + 1];
#pragma unroll
                for (int nt = 0; nt < 4; nt++) {
                    int col = n0 + wn * 64 + nt * 16 + l15;
                    half2_t hv;
                    hv.x = (_Float16)(acc[mt][nt][2 * s]     + b0);
                    hv.y = (_Float16)(acc[mt][nt][2 * s + 1] + b1);
                    Yp[(size_t)(mp >> 1) * N + col] = __builtin_bit_cast(unsigned, hv);
                }
            }
        }
    } else {
#pragma unroll
        for (int mt = 0; mt < 4; mt++) {
#pragma unroll
            for (int r = 0; r < 4; r++) {
                int m = m0 + wm * 64 + mt * 16 + rq * 4 + r;
                float bs = bias[m];
                OutT* yp = Yb + (size_t)m * N + n0 + wn * 64;
#pragma unroll
                for (int nt = 0; nt < 4; nt++)
                    yp[nt * 16 + l15] = (OutT)(acc[mt][nt][r] + bs);
            }
        }
    }
}

// ----------------------------------------------------------------------------
// Attention partial, pipe-split version.
// QK: k-row loaded once per i (coalesced), served to all j via __shfl (DS pipe).
// PV: v loaded per (i,j) directly from L1 (VMEM pipe), lane x reads the 16
// packed dwords of pixel (yy, clamp(xx)); invalid lanes multiply by 0.
// The two streams occupy different HW pipes and overlap across 13 waves/CU.
// Zero-padding: OOB neighbors add exp(rpb) to denom, v contribution = 0.
// ----------------------------------------------------------------------------
template <int KS, int DIL>
__device__ __forceinline__ void attn_part(const unsigned* __restrict__ base,
                                          const float* __restrict__ rp,
                                          int h, int y, int i0, int i1,
                                          float* __restrict__ acc,
                                          float& denom) {
    const int x = threadIdx.x;   // 0..63

    const unsigned* qb = base + (size_t)(h * 16) * PIX + y * W_IMG + x;
    const unsigned* kb = base + (size_t)(128 + h * 16) * PIX + x;
    const unsigned* vb = base + (size_t)(256 + h * 16) * PIX;   // no lane offset

    half2_t qh[16];
#pragma unroll
    for (int d2 = 0; d2 < 16; d2++)
        qh[d2] = __builtin_bit_cast(half2_t, qb[(size_t)d2 * PIX]);

#pragma unroll 1
    for (int i = i0; i < i1; i++) {
        const int yy = y + (i - KS / 2) * DIL;
        const float* rrow = rp + i * KS;
        if ((unsigned)yy < (unsigned)H_IMG) {
            int kr[16];
            const unsigned* ko = kb + yy * W_IMG;
#pragma unroll
            for (int d2 = 0; d2 < 16; d2++)
                kr[d2] = (int)ko[(size_t)d2 * PIX];
            const unsigned* vrow = vb + yy * W_IMG;
#pragma unroll
            for (int j = 0; j < KS; j++) {
                const int xx = x + (j - KS / 2) * DIL;
                const int src = xx & 63;
                const bool vx = (unsigned)xx < (unsigned)W_IMG;
                const int xc = xx < 0 ? 0 : (xx > 63 ? 63 : xx);
                // v direct-load (VMEM pipe, L1-hit): independent of the QK chain
                unsigned vld[16];
#pragma unroll
                for (int d2 = 0; d2 < 16; d2++)
                    vld[d2] = vrow[(size_t)d2 * PIX + xc];
                // QK via lane crossbar (DS pipe), 4 parallel fdot2 chains
                float s0 = 0.f, s1 = 0.f, s2 = 0.f, s3 = 0.f;
#pragma unroll
                for (int d2 = 0; d2 < 16; d2 += 4) {
                    half2_t k0 = __builtin_bit_cast(half2_t, __shfl(kr[d2 + 0], src));
                    half2_t k1 = __builtin_bit_cast(half2_t, __shfl(kr[d2 + 1], src));
                    half2_t k2 = __builtin_bit_cast(half2_t, __shfl(kr[d2 + 2], src));
                    half2_t k3 = __builtin_bit_cast(half2_t, __shfl(kr[d2 + 3], src));
#if __has_builtin(__builtin_amdgcn_fdot2)
                    s0 = __builtin_amdgcn_fdot2(qh[d2 + 0], k0, s0, false);
                    s1 = __builtin_amdgcn_fdot2(qh[d2 + 1], k1, s1, false);
                    s2 = __builtin_amdgcn_fdot2(qh[d2 + 2], k2, s2, false);
                    s3 = __builtin_amdgcn_fdot2(qh[d2 + 3], k3, s3, false);
#else
                    s0 += (float)qh[d2+0].x * (float)k0.x + (float)qh[d2+0].y * (float)k0.y;
                    s1 += (float)qh[d2+1].x * (float)k1.x + (float)qh[d2+1].y * (float)k1.y;
                    s2 += (float)qh[d2+2].x * (float)k2.x + (float)qh[d2+2].y * (float)k2.y;
                    s3 += (float)qh[d2+3].x * (float)k3.x + (float)qh[d2+3].y * (float)k3.y;
#endif
                }
                const float rb = rrow[j];
                float logit = fmaf((s0 + s1) + (s2 + s3), ATT_SCALE, rb);
                logit = vx ? logit : rb;
                const float wgt = __expf(logit);
                denom += wgt;
                const float wv = vx ? wgt : 0.f;
#pragma unroll
                for (int d2 = 0; d2 < 16; d2++) {
                    half2_t vv = __builtin_bit_cast(half2_t, vld[d2]);
                    acc[2 * d2]     += wv * (float)vv.x;
                    acc[2 * d2 + 1] += wv * (float)vv.y;
                }
            }
        } else {
#pragma unroll
            for (int j = 0; j < KS; j++) denom += __expf(rrow[j]);
        }
    }
}

__device__ __forceinline__ void store_attn(_Float16* __restrict__ op,
                                           const float* __restrict__ acc,
                                           float denom) {
    const float inv = 1.f / denom;
#pragma unroll
    for (int g = 0; g < 4; g++) {
        half8_t hv;
#pragma unroll
        for (int e = 0; e < 8; e++) hv[e] = (_Float16)(acc[g * 8 + e] * inv);
        *(half8_t*)(op + g * 8) = hv;
    }
}

// ----------------------------------------------------------------------------
// Attention v6: one block = one (b, y) row, 13 near-equal waves (see R8).
// Grid = 256 identical blocks -> 1/CU, no tail. Partials merge via LDS.
// ----------------------------------------------------------------------------
__launch_bounds__(832)
__global__ void attn_v6(const unsigned* __restrict__ qkv,   // pair dwords [b][384][PIX]
                        const float* __restrict__ rpb0,
                        const float* __restrict__ rpb1,
                        const float* __restrict__ rpb2,
                        _Float16* __restrict__ outT) {      // fp16 [b][PIX][CDIM]
    __shared__ float P[9][33][64];   // 76 KB partial buffer
    const int b  = blockIdx.x;
    const int y  = blockIdx.y;
    const int x  = threadIdx.x;
    const int ty = threadIdx.y;

    const unsigned* base = qkv + (size_t)b * (QKV_C / 2) * PIX;
    const int p = y * W_IMG + x;

    float acc[HD];
#pragma unroll
    for (int d = 0; d < HD; d++) acc[d] = 0.f;
    float denom = 0.f;

    int h;
    int slot = -1;
    if (ty < 4) {
        h = ty;
        attn_part<5, 1>(base, rpb0 + h * 25, h, y, 0, 5, acc, denom);
    } else if (ty < 10) {
        const int idx = ty - 4;
        h = 4 + (idx >> 1);
        const int half = idx & 1;
        attn_part<7, 2>(base, rpb1 + (h - 4) * 49, h, y, half ? 4 : 0, half ? 7 : 4, acc, denom);
        slot = idx;
    } else {
        h = 7;
        const int t3 = ty - 10;
        attn_part<9, 3>(base, rpb2, h, y, 3 * t3, 3 * t3 + 3, acc, denom);
        slot = 6 + t3;
    }

    _Float16* op = outT + ((size_t)b * PIX + p) * CDIM + h * HD;

    if (slot < 0) {
        store_attn(op, acc, denom);      // k5 heads: no merge needed
    } else {
#pragma unroll
        for (int d = 0; d < HD; d++) P[slot][d][x] = acc[d];
        P[slot][HD][x] = denom;
    }
    __syncthreads();

    if (ty == 4 || ty == 6 || ty == 8) {          // merge k7 halves
        const int s0 = ty - 4;
        float m[HD];
#pragma unroll
        for (int d = 0; d < HD; d++) m[d] = P[s0][d][x] + P[s0 + 1][d][x];
        store_attn(op, m, P[s0][HD][x] + P[s0 + 1][HD][x]);
    } else if (ty == 10) {                         // merge k9 thirds
        float m[HD];
#pragma unroll
        for (int d = 0; d < HD; d++) m[d] = P[6][d][x] + P[7][d][x] + P[8][d][x];
        store_attn(op, m, P[6][HD][x] + P[7][HD][x] + P[8][HD][x]);
    }
}

// ----------------------------------------------------------------------------
extern "C" void kernel_launch(void* const* d_in, const int* in_sizes, int n_in,
                              void* d_out, int out_size, void* d_ws, size_t ws_size,
                              hipStream_t stream) {
    const float* x      = (const float*)d_in[0];
    const float* qkv_w  = (const float*)d_in[1];
    const float* qkv_b  = (const float*)d_in[2];
    const float* proj_w = (const float*)d_in[3];
    const float* proj_b = (const float*)d_in[4];
    const float* rpb0   = (const float*)d_in[5];
    const float* rpb1   = (const float*)d_in[6];
    const float* rpb2   = (const float*)d_in[7];
    float* out = (float*)d_out;

    // Workspace: qkv16 24 MB | T16 8 MB (xT16, then overwritten by attn out) | W16+P16
    char* ws = (char*)d_ws;
    _Float16* qkv16 = (_Float16*)ws;
    _Float16* T16   = (_Float16*)(ws + (size_t)NB * QKV_C * PIX * 2);
    _Float16* W16   = T16 + (size_t)NB * PIX * CDIM;
    _Float16* P16   = W16 + (size_t)QKV_C * CDIM;

    const int nw = QKV_C * CDIM, np = CDIM * CDIM;

    // Transpose x + convert both weight matrices, one dispatch
    transpose_cvt<<<dim3(PIX / 64, CDIM / 64, NB + 1), dim3(64, 4), 0, stream>>>(
        x, T16, qkv_w, nw, proj_w, np, W16, P16);

    // QKV GEMM, pair-interleaved fp16 output
    gemm16<_Float16, true><<<dim3(PIX / 128, QKV_C / 128, NB), dim3(256), 0, stream>>>(
        W16, T16, qkv_b, qkv16, QKV_C, CDIM, PIX);

    // Attention v6: 256 identical 13-wave blocks, DS/VMEM pipe-split
    attn_v6<<<dim3(NB, H_IMG), dim3(64, 13), 0, stream>>>(
        (const unsigned*)qkv16, rpb0, rpb1, rpb2, T16);

    // Proj GEMM reads attention output in place
    gemm16<float, false><<<dim3(PIX / 128, CDIM / 128, NB), dim3(256), 0, stream>>>(
        P16, T16, proj_b, out, CDIM, CDIM, PIX);
}

// Round 10
// 151.558 us; speedup vs baseline: 1.5118x; 1.5118x over previous
//
#include <hip/hip_runtime.h>
#include <math.h>

#define H_IMG 64
#define W_IMG 64
#define PIX   (H_IMG * W_IMG)   // 4096
#define NB    4
#define NHEADS 8
#define HD    32
#define CDIM  256
#define QKV_C 768
#define ATT_SCALE 0.17677669529663687f  // 32^-0.5

typedef _Float16 half8_t __attribute__((ext_vector_type(8)));
typedef _Float16 half2_t __attribute__((ext_vector_type(2)));
typedef float f32x4 __attribute__((ext_vector_type(4)));

// Direct global->LDS DMA, 16B per lane. LDS dest = wave-uniform base + lane*16.
__device__ __forceinline__ void gld_lds16(const _Float16* g, _Float16* l) {
    __builtin_amdgcn_global_load_lds((const __attribute__((address_space(1))) void*)g,
                                     (__attribute__((address_space(3))) void*)l, 16, 0, 0);
}

// ----------------------------------------------------------------------------
// Transpose+convert x [b][C][PIX] f32 -> [b][PIX][C] f16, AND (z==NB slice)
// convert both weight matrices to fp16. One dispatch.
// ----------------------------------------------------------------------------
__launch_bounds__(256)
__global__ void transpose_cvt(const float* __restrict__ src, _Float16* __restrict__ dst,
                              const float* __restrict__ w1, int n1,
                              const float* __restrict__ w2, int n2,
                              _Float16* __restrict__ d1, _Float16* __restrict__ d2) {
    const int tx = threadIdx.x;
    const int ty = threadIdx.y;
    if (blockIdx.z == NB) {
        const int bid = blockIdx.y * 64 + blockIdx.x;          // 0..255
        int tid = bid * 256 + ty * 64 + tx;                    // 0..65535
        const int total = n1 + n2;
        for (int i = tid; i < total; i += 65536) {
            if (i < n1) d1[i] = (_Float16)w1[i];
            else        d2[i - n1] = (_Float16)w2[i - n1];
        }
        return;
    }
    __shared__ _Float16 tl[64][66];
    const int b  = blockIdx.z;
    const int p0 = blockIdx.x * 64;
    const int c0 = blockIdx.y * 64;
    const float* s = src + (size_t)b * CDIM * PIX;
    _Float16* d = dst + (size_t)b * PIX * CDIM;
#pragma unroll
    for (int cc = ty; cc < 64; cc += 4)
        tl[cc][tx] = (_Float16)s[(size_t)(c0 + cc) * PIX + p0 + tx];
    __syncthreads();
#pragma unroll
    for (int pp = ty; pp < 64; pp += 4)
        d[(size_t)(p0 + pp) * CDIM + c0 + tx] = tl[tx][pp];
}

// ----------------------------------------------------------------------------
// fp16 MFMA GEMM with global_load_lds staging.
// Y[b][m][n] = sum_k A[m][k] * BT[b][n][k] + bias[m]
// 128x128 tile, BK=32, 4 waves (2x2), each 64x64 via 4x4 16x16x32 MFMA.
// LDS tiles UNPADDED row-major (64B/row): exactly the lane-linear layout
// global_load_lds requires (wave-uniform base + lane*16B). Per k-iter each
// wave issues 2 A-chunks + 2 B-chunks (1KB each), no VGPR round-trip.
// ----------------------------------------------------------------------------
template <typename OutT, bool PAIR>
__launch_bounds__(256)
__global__ void gemm16(const _Float16* __restrict__ A,
                       const _Float16* __restrict__ BT,
                       const float* __restrict__ bias,
                       OutT* __restrict__ Y,
                       int M, int K, int N) {
    __shared__ _Float16 Asl[128 * 32];   // 8 KB, row stride 32 halves
    __shared__ _Float16 Bsl[128 * 32];
    const int b = blockIdx.z;
    const _Float16* Bb = BT + (size_t)b * N * K;
    OutT* Yb = Y + (size_t)b * M * N;
    const int m0 = blockIdx.y * 128;
    const int n0 = blockIdx.x * 128;
    const int t    = threadIdx.x;
    const int lane = t & 63;
    const int w    = t >> 6;
    const int wm = w >> 1, wn = w & 1;
    const int l15 = lane & 15;
    const int kq  = (lane >> 4) * 8;

    // staging geometry: chunk c (0..7) covers rows c*16 + lane/4, seg (lane&3)*8 halves
    const int c0i = w * 2, c1i = w * 2 + 1;
    const int rA0 = c0i * 16 + (lane >> 2);
    const int rA1 = c1i * 16 + (lane >> 2);
    const int seg = (lane & 3) * 8;

    f32x4 acc[4][4];
#pragma unroll
    for (int mt = 0; mt < 4; mt++)
#pragma unroll
        for (int nt = 0; nt < 4; nt++)
            acc[mt][nt] = (f32x4){0.f, 0.f, 0.f, 0.f};

    for (int k0 = 0; k0 < K; k0 += 32) {
        __syncthreads();
        gld_lds16(A  + (size_t)(m0 + rA0) * K + k0 + seg, &Asl[c0i * 512]);
        gld_lds16(A  + (size_t)(m0 + rA1) * K + k0 + seg, &Asl[c1i * 512]);
        gld_lds16(Bb + (size_t)(n0 + rA0) * K + k0 + seg, &Bsl[c0i * 512]);
        gld_lds16(Bb + (size_t)(n0 + rA1) * K + k0 + seg, &Bsl[c1i * 512]);
        __syncthreads();
        half8_t af[4], bf[4];
#pragma unroll
        for (int mt = 0; mt < 4; mt++)
            af[mt] = *(const half8_t*)&Asl[(wm * 64 + mt * 16 + l15) * 32 + kq];
#pragma unroll
        for (int nt = 0; nt < 4; nt++)
            bf[nt] = *(const half8_t*)&Bsl[(wn * 64 + nt * 16 + l15) * 32 + kq];
#pragma unroll
        for (int mt = 0; mt < 4; mt++)
#pragma unroll
            for (int nt = 0; nt < 4; nt++)
                acc[mt][nt] = __builtin_amdgcn_mfma_f32_16x16x32_f16(
                    af[mt], bf[nt], acc[mt][nt], 0, 0, 0);
    }

    const int rq = lane >> 4;
    if constexpr (PAIR) {
        unsigned* Yp = (unsigned*)Yb;   // (M/2) x N dwords
#pragma unroll
        for (int mt = 0; mt < 4; mt++) {
#pragma unroll
            for (int s = 0; s < 2; s++) {
                int mp = m0 + wm * 64 + mt * 16 + rq * 4 + 2 * s;
                float b0 = bias[mp], b1 = bias[mp + 1];
#pragma unroll
                for (int nt = 0; nt < 4; nt++) {
                    int col = n0 + wn * 64 + nt * 16 + l15;
                    half2_t hv;
                    hv.x = (_Float16)(acc[mt][nt][2 * s]     + b0);
                    hv.y = (_Float16)(acc[mt][nt][2 * s + 1] + b1);
                    Yp[(size_t)(mp >> 1) * N + col] = __builtin_bit_cast(unsigned, hv);
                }
            }
        }
    } else {
#pragma unroll
        for (int mt = 0; mt < 4; mt++) {
#pragma unroll
            for (int r = 0; r < 4; r++) {
                int m = m0 + wm * 64 + mt * 16 + rq * 4 + r;
                float bs = bias[m];
                OutT* yp = Yb + (size_t)m * N + n0 + wn * 64;
#pragma unroll
                for (int nt = 0; nt < 4; nt++)
                    yp[nt * 16 + l15] = (OutT)(acc[mt][nt][r] + bs);
            }
        }
    }
}

// ----------------------------------------------------------------------------
// Attention partial (R8/v5 version — known good, no spills).
// QK and PV both via __shfl from registers; 4 parallel fdot2 chains.
// Zero-padding: OOB adds exp(rpb) to denom, v = 0.
// ----------------------------------------------------------------------------
template <int KS, int DIL>
__device__ __forceinline__ void attn_part(const unsigned* __restrict__ base,
                                          const float* __restrict__ rp,
                                          int h, int y, int i0, int i1,
                                          float* __restrict__ acc,
                                          float& denom) {
    const int x = threadIdx.x;   // 0..63

    const unsigned* qb = base + (size_t)(h * 16) * PIX + y * W_IMG + x;
    const unsigned* kb = base + (size_t)(128 + h * 16) * PIX + x;
    const unsigned* vb = base + (size_t)(256 + h * 16) * PIX + x;

    half2_t qh[16];
#pragma unroll
    for (int d2 = 0; d2 < 16; d2++)
        qh[d2] = __builtin_bit_cast(half2_t, qb[(size_t)d2 * PIX]);

#pragma unroll 1
    for (int i = i0; i < i1; i++) {
        const int yy = y + (i - KS / 2) * DIL;
        const float* rrow = rp + i * KS;
        if ((unsigned)yy < (unsigned)H_IMG) {
            int kr[16], vr[16];
            const unsigned* ko = kb + yy * W_IMG;
            const unsigned* vo = vb + yy * W_IMG;
#pragma unroll
            for (int d2 = 0; d2 < 16; d2++) {
                kr[d2] = (int)ko[(size_t)d2 * PIX];
                vr[d2] = (int)vo[(size_t)d2 * PIX];
            }
#pragma unroll
            for (int j = 0; j < KS; j++) {
                const int xx = x + (j - KS / 2) * DIL;
                const int src = xx & 63;
                const bool vx = (unsigned)xx < (unsigned)W_IMG;
                float s0 = 0.f, s1 = 0.f, s2 = 0.f, s3 = 0.f;
#pragma unroll
                for (int d2 = 0; d2 < 16; d2 += 4) {
                    half2_t k0 = __builtin_bit_cast(half2_t, __shfl(kr[d2 + 0], src));
                    half2_t k1 = __builtin_bit_cast(half2_t, __shfl(kr[d2 + 1], src));
                    half2_t k2 = __builtin_bit_cast(half2_t, __shfl(kr[d2 + 2], src));
                    half2_t k3 = __builtin_bit_cast(half2_t, __shfl(kr[d2 + 3], src));
#if __has_builtin(__builtin_amdgcn_fdot2)
                    s0 = __builtin_amdgcn_fdot2(qh[d2 + 0], k0, s0, false);
                    s1 = __builtin_amdgcn_fdot2(qh[d2 + 1], k1, s1, false);
                    s2 = __builtin_amdgcn_fdot2(qh[d2 + 2], k2, s2, false);
                    s3 = __builtin_amdgcn_fdot2(qh[d2 + 3], k3, s3, false);
#else
                    s0 += (float)qh[d2+0].x * (float)k0.x + (float)qh[d2+0].y * (float)k0.y;
                    s1 += (float)qh[d2+1].x * (float)k1.x + (float)qh[d2+1].y * (float)k1.y;
                    s2 += (float)qh[d2+2].x * (float)k2.x + (float)qh[d2+2].y * (float)k2.y;
                    s3 += (float)qh[d2+3].x * (float)k3.x + (float)qh[d2+3].y * (float)k3.y;
#endif
                }
                const float rb = rrow[j];
                float logit = fmaf((s0 + s1) + (s2 + s3), ATT_SCALE, rb);
                logit = vx ? logit : rb;
                const float wgt = __expf(logit);
                denom += wgt;
                const float wv = vx ? wgt : 0.f;
#pragma unroll
                for (int d2 = 0; d2 < 16; d2++) {
                    half2_t vv = __builtin_bit_cast(half2_t, __shfl(vr[d2], src));
                    acc[2 * d2]     += wv * (float)vv.x;
                    acc[2 * d2 + 1] += wv * (float)vv.y;
                }
            }
        } else {
#pragma unroll
            for (int j = 0; j < KS; j++) denom += __expf(rrow[j]);
        }
    }
}

__device__ __forceinline__ void store_attn(_Float16* __restrict__ op,
                                           const float* __restrict__ acc,
                                           float denom) {
    const float inv = 1.f / denom;
#pragma unroll
    for (int g = 0; g < 4; g++) {
        half8_t hv;
#pragma unroll
        for (int e = 0; e < 8; e++) hv[e] = (_Float16)(acc[g * 8 + e] * inv);
        *(half8_t*)(op + g * 8) = hv;
    }
}

// ----------------------------------------------------------------------------
// Attention v5 (R8): one block = one (b, y) row, 13 near-equal waves:
//   ty 0..3  : k5 heads 0..3, all 5 key-rows
//   ty 4..9  : k7 heads 4..6, rows [0,4) / [4,7)
//   ty 10..12: k9 head 7, rows [0,3)/[3,6)/[6,9)
// Grid = 256 identical blocks -> 1/CU, 13 resident waves, no tail.
// ----------------------------------------------------------------------------
__launch_bounds__(832)
__global__ void attn_v5(const unsigned* __restrict__ qkv,   // pair dwords [b][384][PIX]
                        const float* __restrict__ rpb0,
                        const float* __restrict__ rpb1,
                        const float* __restrict__ rpb2,
                        _Float16* __restrict__ outT) {      // fp16 [b][PIX][CDIM]
    __shared__ float P[9][33][64];   // 76 KB partial buffer
    const int b  = blockIdx.x;
    const int y  = blockIdx.y;
    const int x  = threadIdx.x;
    const int ty = threadIdx.y;

    const unsigned* base = qkv + (size_t)b * (QKV_C / 2) * PIX;
    const int p = y * W_IMG + x;

    float acc[HD];
#pragma unroll
    for (int d = 0; d < HD; d++) acc[d] = 0.f;
    float denom = 0.f;

    int h;
    int slot = -1;
    if (ty < 4) {
        h = ty;
        attn_part<5, 1>(base, rpb0 + h * 25, h, y, 0, 5, acc, denom);
    } else if (ty < 10) {
        const int idx = ty - 4;
        h = 4 + (idx >> 1);
        const int half = idx & 1;
        attn_part<7, 2>(base, rpb1 + (h - 4) * 49, h, y, half ? 4 : 0, half ? 7 : 4, acc, denom);
        slot = idx;
    } else {
        h = 7;
        const int t3 = ty - 10;
        attn_part<9, 3>(base, rpb2, h, y, 3 * t3, 3 * t3 + 3, acc, denom);
        slot = 6 + t3;
    }

    _Float16* op = outT + ((size_t)b * PIX + p) * CDIM + h * HD;

    if (slot < 0) {
        store_attn(op, acc, denom);      // k5 heads: no merge needed
    } else {
#pragma unroll
        for (int d = 0; d < HD; d++) P[slot][d][x] = acc[d];
        P[slot][HD][x] = denom;
    }
    __syncthreads();

    if (ty == 4 || ty == 6 || ty == 8) {          // merge k7 halves
        const int s0 = ty - 4;
        float m[HD];
#pragma unroll
        for (int d = 0; d < HD; d++) m[d] = P[s0][d][x] + P[s0 + 1][d][x];
        store_attn(op, m, P[s0][HD][x] + P[s0 + 1][HD][x]);
    } else if (ty == 10) {                         // merge k9 thirds
        float m[HD];
#pragma unroll
        for (int d = 0; d < HD; d++) m[d] = P[6][d][x] + P[7][d][x] + P[8][d][x];
        store_attn(op, m, P[6][HD][x] + P[7][HD][x] + P[8][HD][x]);
    }
}

// ----------------------------------------------------------------------------
extern "C" void kernel_launch(void* const* d_in, const int* in_sizes, int n_in,
                              void* d_out, int out_size, void* d_ws, size_t ws_size,
                              hipStream_t stream) {
    const float* x      = (const float*)d_in[0];
    const float* qkv_w  = (const float*)d_in[1];
    const float* qkv_b  = (const float*)d_in[2];
    const float* proj_w = (const float*)d_in[3];
    const float* proj_b = (const float*)d_in[4];
    const float* rpb0   = (const float*)d_in[5];
    const float* rpb1   = (const float*)d_in[6];
    const float* rpb2   = (const float*)d_in[7];
    float* out = (float*)d_out;

    // Workspace: qkv16 24 MB | T16 8 MB (xT16, then overwritten by attn out) | W16+P16
    char* ws = (char*)d_ws;
    _Float16* qkv16 = (_Float16*)ws;
    _Float16* T16   = (_Float16*)(ws + (size_t)NB * QKV_C * PIX * 2);
    _Float16* W16   = T16 + (size_t)NB * PIX * CDIM;
    _Float16* P16   = W16 + (size_t)QKV_C * CDIM;

    const int nw = QKV_C * CDIM, np = CDIM * CDIM;

    // Transpose x + convert both weight matrices, one dispatch
    transpose_cvt<<<dim3(PIX / 64, CDIM / 64, NB + 1), dim3(64, 4), 0, stream>>>(
        x, T16, qkv_w, nw, proj_w, np, W16, P16);

    // QKV GEMM, pair-interleaved fp16 output
    gemm16<_Float16, true><<<dim3(PIX / 128, QKV_C / 128, NB), dim3(256), 0, stream>>>(
        W16, T16, qkv_b, qkv16, QKV_C, CDIM, PIX);

    // Attention v5: 256 identical 13-wave blocks
    attn_v5<<<dim3(NB, H_IMG), dim3(64, 13), 0, stream>>>(
        (const unsigned*)qkv16, rpb0, rpb1, rpb2, T16);

    // Proj GEMM reads attention output in place
    gemm16<float, false><<<dim3(PIX / 128, CDIM / 128, NB), dim3(256), 0, stream>>>(
        P16, T16, proj_b, out, CDIM, CDIM, PIX);
}